// Round 11
// baseline (6475.333 us; speedup 1.0000x reference)
//
#include <hip/hip_runtime.h>
#include <cstdint>
#include <cstddef>

// ============================================================================
// 4-layer LSTM (B=128, T=1024, D=128, H={100,100,200,200}) + linear head.
// R18 = R17 resubmitted verbatim (round-10 bench was an infra failure:
// "MI355X container failed twice" — no kernel verdict obtained).
// R17 = R16 (best, 5826us) + ASYNC SIBLING-FLAG PREFETCH:
//  - sibling + backpressure flag loads are ISSUED at the top of each step
//    (relaxed atomic loads into registers, no wait); the x-part compute
//    (~1-1.5us) covers their latency; at phase B the early observation is
//    checked first and the spin runs only if insufficient (rare: siblings
//    are in lockstep, their flag=t landed during our step t-1 publish).
//  - R16's monotonic caches kept (they absorb upstream/backpressure skew;
//    the early-issue only fires when the cache is insufficient).
//  - protocol/scopes/loads byte-identical to R16 otherwise. The early load
//    is just an earlier first observation of a monotonic flag; fallback
//    spin is unchanged => cannot deadlock, cannot consume unpublished data
//    (acquire fence before data loads preserved).
// R14/R15 lesson kept: agent scope on BOTH sides; no L2-local exchange.
// ============================================================================

#define AGENT __HIP_MEMORY_SCOPE_AGENT
#define FSTR 64   // u32 stride between flags (256B sector per flag)

typedef __attribute__((ext_vector_type(8))) short  short8;
typedef __attribute__((ext_vector_type(4))) float  f32x4;

__device__ __forceinline__ unsigned short f2bf(float x){
  unsigned u = __float_as_uint(x);
  unsigned r = u + 0x7FFFu + ((u >> 16) & 1u);   // RN-even to bf16
  return (unsigned short)(r >> 16);
}
__device__ __forceinline__ float bf2f(unsigned short h){
  return __uint_as_float(((unsigned)h) << 16);
}
__device__ __forceinline__ float sigmoidf_(float x){ return 1.f / (1.f + __expf(-x)); }
__device__ __forceinline__ float tanhf_(float x){
  return 1.f - 2.f / (1.f + __expf(2.f * x));
}

// spin until *p >= v; returns the last observed value (cached by caller).
__device__ __forceinline__ unsigned spin_ge(const unsigned* p, unsigned v){
  unsigned ob;
  #pragma unroll 1
  for (int i = 0; i < 32; ++i){
    ob = __hip_atomic_load(p, __ATOMIC_RELAXED, AGENT);
    if (ob >= v) return ob;
  }
  long s = 0;
  #pragma unroll 1
  while ((ob = __hip_atomic_load(p, __ATOMIC_RELAXED, AGENT)) < v){
    __builtin_amdgcn_s_sleep(8);               // ~0.2us backoff
    if (++s > (1L << 17)) break;               // fail fast on true deadlock
  }
  return ob;
}

__device__ __forceinline__ void load_hx(const unsigned* base, int w32, int loOff,
                                        short8& ah, short8& al){
  union U { unsigned long long q[2]; short8 v; } uh, ul;
  const unsigned long long* ph = (const unsigned long long*)(base + w32);
  const unsigned long long* pl = (const unsigned long long*)(base + loOff + w32);
  uh.q[0] = __hip_atomic_load(ph + 0, __ATOMIC_RELAXED, AGENT);
  uh.q[1] = __hip_atomic_load(ph + 1, __ATOMIC_RELAXED, AGENT);
  ul.q[0] = __hip_atomic_load(pl + 0, __ATOMIC_RELAXED, AGENT);
  ul.q[1] = __hip_atomic_load(pl + 1, __ATOMIC_RELAXED, AGENT);
  ah = uh.v; al = ul.v;
}

// ---------------------------------------------------------------------------
// Fused pipeline stage (window-8 h slots, per-wave two-phase waits with
// monotonic flag caching + async sibling-flag prefetch).
// XS_IN=true (layer 0): x-part from xs directly (plain cached loads).
// XS_IN=false (layers 1-3): x-part from upstream Hx slots (agent atomics).
// Hx layout per layer: [slot(8)][group(8)][plane hi/lo][16 rows][RS u32].
// Flags: index (g*16 + member) * FSTR.
// ---------------------------------------------------------------------------
template<int H, int HP, int P, bool XS_IN>
__device__ __forceinline__ void rec_stage(
    const float* __restrict__ xs,
    const float* __restrict__ Wx, const float* __restrict__ Wh,
    const float* __restrict__ bias, int HprevReal,
    const unsigned* __restrict__ HxUp, unsigned* __restrict__ HxOwn,
    const unsigned* __restrict__ flgUp, unsigned* __restrict__ flgOwn,
    unsigned* __restrict__ flgDn, int PUp, int PDn,
    float* __restrict__ cstate, float* __restrict__ hlast,
    int g, int m, int t0, int TC, int Tlast, char* smem)
{
  constexpr int HHM  = H / P;                 // 20
  constexpr int COLS = 4 * HHM;               // 80
  constexpr int ZSTR = COLS + 1;              // zbuf row stride (pad)
  constexpr int KPo  = ((H + 31)/32)*32;      // own-h padded K
  constexpr int RSo  = KPo / 2;               // own Hx row stride (u32)
  constexpr int RSp  = HP / 2;                // upstream Hx row stride
  constexpr int KX   = HP;                    // x-part K (xs D or upstream Hp)
  constexpr int KALL = KX + KPo;
  constexpr int KTX  = KX / 32;
  constexpr int KTH  = KPo / 32;
  constexpr int KSTR = KALL + 8;
  constexpr int NT   = COLS / 16;             // 5
  constexpr int NE   = 16 * HHM / 2;          // 160
  constexpr int PR   = HHM / 2;               // 10
  constexpr int N4H  = 4 * H;
  constexpr int SLOTo = 2*16*RSo;             // u32 per (slot,group), own
  constexpr int SLOTp = 2*16*RSp;             // u32 per (slot,group), upstream

  unsigned short* whT_hi = (unsigned short*)smem;
  unsigned short* whT_lo = whT_hi + COLS*KSTR;
  float* zbuf = (float*)(whT_lo + COLS*KSTR);   // [16][ZSTR]

  const int tid  = threadIdx.x;
  const int row0 = g * 16;
  const int lane = tid & 63, wave = tid >> 6;
  const int ln15 = lane & 15, quad = lane >> 4;

  // stage concatenated weight strip [col][k] = [Wx; Wh], hi/lo bf16
  for (int e = tid; e < COLS*KALL; e += 256){
    const int k = e / COLS, c = e - k*COLS;
    const int gate = c / HHM, hh = c - gate*HHM;
    const int col = gate*H + m*HHM + hh;
    float w = 0.f;
    if (k < KX){ if (k < HprevReal) w = Wx[(size_t)k*N4H + col]; }
    else { const int k2 = k - KX; if (k2 < H) w = Wh[(size_t)k2*N4H + col]; }
    const unsigned short hi = f2bf(w);
    whT_hi[c*KSTR + k] = hi;
    whT_lo[c*KSTR + k] = f2bf(w - bf2f(hi));
  }

  const int r_g  = tid / PR;
  const int hh0  = 2*(tid - r_g*PR);
  const int kidx = m*HHM + hh0;
  float c0 = 0.f, c1 = 0.f;
  if (tid < NE && t0 > 0){
    const float2 cv = *(const float2*)&cstate[(size_t)(row0 + r_g)*H + kidx];
    c0 = cv.x; c1 = cv.y;
  }
  float2 bv[4] = {};
  if (tid < NE){
    #pragma unroll
    for (int gate = 0; gate < 4; ++gate)
      bv[gate] = *(const float2*)&bias[gate*H + kidx];
  }
  __syncthreads();

  const int g16 = g*16;

  // per-lane spin roles + monotonic caches
  const bool sibLane = (lane < P && lane != m);
  const bool dnLane  = (PDn > 0 && lane >= 40 && lane < 40 + PDn);
  const unsigned* sibP = sibLane ? &flgOwn[(size_t)(g16 + lane)*FSTR] : nullptr;
  const unsigned* dnP  = dnLane  ? &flgDn[(size_t)(g16 + (lane-40))*FSTR] : nullptr;
  unsigned upC = 0, sibC = 0, dnC = 0;

  for (int tl = 0; tl < TC; ++tl){
    const int t = t0 + tl;

    // ---- EARLY ISSUE: sibling/backpressure flag loads (no wait). The
    // x-part below covers their latency; checked at phase B. ----
    unsigned sibE = 0, dnE = 0;
    const bool sibNeed = sibLane && sibC < (unsigned)t;
    const bool dnNeed  = dnLane && t >= 8 && dnC < (unsigned)(t-7);
    if (sibNeed) sibE = __hip_atomic_load(sibP, __ATOMIC_RELAXED, AGENT);
    if (dnNeed)  dnE  = __hip_atomic_load(dnP,  __ATOMIC_RELAXED, AGENT);

    // ---- phase A: per-wave upstream wait (layers 1-3), cached ----
    if constexpr (!XS_IN){
      if (lane < PUp && upC < (unsigned)(t+1))
        upC = spin_ge(&flgUp[(size_t)(g16 + lane)*FSTR], (unsigned)(t+1));
      __builtin_amdgcn_fence(__ATOMIC_ACQUIRE, "wavefront");
    }

    f32x4 acc[2];
    acc[0] = (f32x4){0.f,0.f,0.f,0.f};
    acc[1] = (f32x4){0.f,0.f,0.f,0.f};
    auto do_tile = [&](const short8& a_h, const short8& a_l, int koW){
      #pragma unroll
      for (int s = 0; s < 2; ++s){
        const int nt = wave + 4*s;
        if (nt < NT){
          const int boff = (nt*16 + ln15)*KSTR + quad*8 + koW;
          const short8 b_h = *(const short8*)&whT_hi[boff];
          const short8 b_l = *(const short8*)&whT_lo[boff];
          acc[s] = __builtin_amdgcn_mfma_f32_16x16x32_bf16(a_h, b_h, acc[s], 0,0,0);
          acc[s] = __builtin_amdgcn_mfma_f32_16x16x32_bf16(a_l, b_h, acc[s], 0,0,0);
          acc[s] = __builtin_amdgcn_mfma_f32_16x16x32_bf16(a_h, b_l, acc[s], 0,0,0);
        }
      }
    };

    // x-part MFMA: xs-direct (L0) or upstream slot (L1-3)
    if constexpr (XS_IN){
      const float* xp = xs + (size_t)(row0 + ln15)*(1024*128)
                           + (size_t)t*128 + quad*8;
      #pragma unroll
      for (int kt = 0; kt < KTX; ++kt){
        const float4 v0 = *(const float4*)(xp + kt*32);
        const float4 v1 = *(const float4*)(xp + kt*32 + 4);
        const float xv[8] = {v0.x, v0.y, v0.z, v0.w, v1.x, v1.y, v1.z, v1.w};
        union SU { unsigned short u[8]; short8 v; } sh, sl;
        #pragma unroll
        for (int j = 0; j < 8; ++j){
          const unsigned short hi = f2bf(xv[j]);
          sh.u[j] = hi;
          sl.u[j] = f2bf(xv[j] - bf2f(hi));
        }
        do_tile(sh.v, sl.v, kt*32);
      }
    } else {
      const unsigned* up = HxUp + ((size_t)(t & 7)*8 + g) * SLOTp;
      #pragma unroll
      for (int kt = 0; kt < KTX; ++kt){
        short8 a_h, a_l;
        load_hx(up, ln15*RSp + kt*16 + quad*4, 16*RSp, a_h, a_l);
        do_tile(a_h, a_l, kt*32);
      }
    }

    // ---- phase B: sibling + backpressure — early observation first ----
    if (sibNeed){
      if (sibE >= (unsigned)t) sibC = sibE;            // detect hidden under x
      else sibC = spin_ge(sibP, (unsigned)t);
    }
    if (dnNeed){
      if (dnE >= (unsigned)(t-7)) dnC = dnE;
      else dnC = spin_ge(dnP, (unsigned)(t-7));
    }
    __builtin_amdgcn_fence(__ATOMIC_ACQUIRE, "wavefront");

    {
      const unsigned* own = HxOwn + ((size_t)((t-1) & 7)*8 + g) * SLOTo;
      #pragma unroll
      for (int kt = 0; kt < KTH; ++kt){
        short8 a_h, a_l;
        load_hx(own, ln15*RSo + kt*16 + quad*4, 16*RSo, a_h, a_l);
        do_tile(a_h, a_l, KX + kt*32);
      }
    }
    {
      #pragma unroll
      for (int s = 0; s < 2; ++s){
        const int nt = wave + 4*s;
        if (nt < NT)
          #pragma unroll
          for (int r = 0; r < 4; ++r)
            zbuf[(quad*4 + r)*ZSTR + nt*16 + ln15] = acc[s][r];
      }
    }
    __syncthreads();   // B1: zbuf ready

    // gates + state update + publish h_t -> own slot t&7
    if (tid < NE){
      const float* zr = zbuf + r_g*ZSTR;
      const float zi0 = zr[0*HHM + hh0]   + bv[0].x, zi1 = zr[0*HHM + hh0+1] + bv[0].y;
      const float zf0 = zr[1*HHM + hh0]   + bv[1].x, zf1 = zr[1*HHM + hh0+1] + bv[1].y;
      const float zg0 = zr[2*HHM + hh0]   + bv[2].x, zg1 = zr[2*HHM + hh0+1] + bv[2].y;
      const float zo0 = zr[3*HHM + hh0]   + bv[3].x, zo1 = zr[3*HHM + hh0+1] + bv[3].y;
      c0 = sigmoidf_(zf0)*c0 + sigmoidf_(zi0)*tanhf_(zg0);
      c1 = sigmoidf_(zf1)*c1 + sigmoidf_(zi1)*tanhf_(zg1);
      const float h0 = sigmoidf_(zo0)*tanhf_(c0);
      const float h1 = sigmoidf_(zo1)*tanhf_(c1);
      const unsigned short h0h = f2bf(h0), h1h = f2bf(h1);
      const unsigned short h0l = f2bf(h0 - bf2f(h0h)), h1l = f2bf(h1 - bf2f(h1h));
      const unsigned whi = ((unsigned)h1h << 16) | (unsigned)h0h;
      const unsigned wlo = ((unsigned)h1l << 16) | (unsigned)h0l;
      unsigned* dst = HxOwn + ((size_t)(t & 7)*8 + g) * SLOTo;
      const int w32 = r_g*RSo + (kidx >> 1);
      __hip_atomic_store(&dst[w32],          whi, __ATOMIC_RELAXED, AGENT);
      __hip_atomic_store(&dst[16*RSo + w32], wlo, __ATOMIC_RELAXED, AGENT);
      if (hlast && t == Tlast-1){
        float2 hv{h0, h1};
        *(float2*)&hlast[(size_t)(row0 + r_g)*H + kidx] = hv;
      }
    }
    __syncthreads();   // B2: vmcnt(0)-drain per wave => h stores LLC-visible
    if (tid == 0)
      __hip_atomic_store(&flgOwn[(size_t)(g16 + m)*FSTR], (unsigned)(t+1),
                         __ATOMIC_RELAXED, AGENT);
  }

  // persist c-state
  if (tid < NE){
    float2 cv{c0, c1};
    *(float2*)&cstate[(size_t)(row0 + r_g)*H + kidx] = cv;
  }
}

struct FusedArgs {
  const float *xs;
  const float *Wx0, *Wx1, *Wx2, *Wx3;
  const float *Wh0, *Wh1, *Wh2, *Wh3;
  const float *b0, *b1, *b2, *b3;
  unsigned *Hx0, *Hx1, *Hx2, *Hx3;
  unsigned *flags;                 // 4 layers x 128 flags x FSTR u32
  float *cst;                      // 4 x 128 x 200
  float *hlast;
  int t0, TC, Tlast;
};

// Blocks: [0,40)=L0, [40,80)=L1, [80,160)=L2, [160,240)=L3.
__global__ __launch_bounds__(256) void lstm_fused(FusedArgs a){
  extern __shared__ char smem[];
  const int b = blockIdx.x;
  constexpr int LF = 128*FSTR;     // u32 per layer's flag region
  unsigned* F = a.flags;
  if (b < 40){
    rec_stage<100, 128, 5, true>(a.xs, a.Wx0, a.Wh0, a.b0, 128,
        nullptr, a.Hx0, nullptr, F + 0*LF, F + 1*LF, 0, 5,
        a.cst + 0*128*200, nullptr, b & 7, b >> 3, a.t0, a.TC, a.Tlast, smem);
  } else if (b < 80){
    const int bb = b - 40;
    rec_stage<100, 128, 5, false>(nullptr, a.Wx1, a.Wh1, a.b1, 100,
        a.Hx0, a.Hx1, F + 0*LF, F + 1*LF, F + 2*LF, 5, 10,
        a.cst + 1*128*200, nullptr, bb & 7, bb >> 3, a.t0, a.TC, a.Tlast, smem);
  } else if (b < 160){
    const int bb = b - 80;
    rec_stage<200, 128, 10, false>(nullptr, a.Wx2, a.Wh2, a.b2, 100,
        a.Hx1, a.Hx2, F + 1*LF, F + 2*LF, F + 3*LF, 5, 10,
        a.cst + 2*128*200, nullptr, bb & 7, bb >> 3, a.t0, a.TC, a.Tlast, smem);
  } else {
    const int bb = b - 160;
    rec_stage<200, 224, 10, false>(nullptr, a.Wx3, a.Wh3, a.b3, 200,
        a.Hx2, a.Hx3, F + 2*LF, F + 3*LF, nullptr, 10, 0,
        a.cst + 3*128*200, a.hlast, bb & 7, bb >> 3, a.t0, a.TC, a.Tlast, smem);
  }
}

// ---------------------------------------------------------------------------
__global__ __launch_bounds__(256) void head_kernel(
    const float* __restrict__ hlast, const float* __restrict__ Wd,
    const float* __restrict__ bd, float* __restrict__ out)
{
  const int e = blockIdx.x*256 + threadIdx.x;
  if (e >= 128*6) return;
  const int b = e / 6, o = e - 6*b;
  float s = bd[o];
  const float* hp = hlast + (size_t)b*200;
  for (int k = 0; k < 200; ++k) s += hp[k] * Wd[k*6 + o];
  out[e] = s;
}

__global__ void fill_sentinel(float* out, int n){
  const int i = blockIdx.x*blockDim.x + threadIdx.x;
  if (i < n) out[i] = 1.0e30f;
}

// ---------------------------------------------------------------------------
extern "C" void kernel_launch(void* const* d_in, const int* in_sizes, int n_in,
                              void* d_out, int out_size, void* d_ws, size_t ws_size,
                              hipStream_t stream)
{
  (void)in_sizes; (void)n_in;
  const float* xs  = (const float*)d_in[0];
  const float* Wx[4] = {(const float*)d_in[1], (const float*)d_in[4],
                        (const float*)d_in[7], (const float*)d_in[10]};
  const float* Wh[4] = {(const float*)d_in[2], (const float*)d_in[5],
                        (const float*)d_in[8], (const float*)d_in[11]};
  const float* bs[4] = {(const float*)d_in[3], (const float*)d_in[6],
                        (const float*)d_in[9], (const float*)d_in[12]};
  const float* Wd = (const float*)d_in[13];
  const float* bd = (const float*)d_in[14];
  float* out = (float*)d_out;

  // ---- workspace layout ----
  char* ws = (char*)d_ws;
  const size_t HXU[4] = {131072, 131072, 229376, 229376};   // u32 per layer
  const size_t HX_TOT = HXU[0]+HXU[1]+HXU[2]+HXU[3];
  const size_t FLAGS_BYTES = (size_t)4*128*FSTR*4;          // 128 KiB
  size_t off = 0;
  const size_t OFF_FLAGS = off; off += FLAGS_BYTES;
  const size_t OFF_HX    = off; off += HX_TOT*4;
  const size_t OFF_CST   = off; off += (size_t)4*128*200*4;
  const size_t OFF_HLAST = off; off += (size_t)128*200*4;
  off = (off + 255) & ~(size_t)255;

  if (ws_size < off){
    fill_sentinel<<<(out_size + 255)/256, 256, 0, stream>>>(out, out_size);
    return;
  }

  unsigned* flags = (unsigned*)(ws + OFF_FLAGS);
  unsigned* Hx0   = (unsigned*)(ws + OFF_HX);
  unsigned* Hx1   = Hx0 + HXU[0];
  unsigned* Hx2   = Hx1 + HXU[1];
  unsigned* Hx3   = Hx2 + HXU[2];
  float* cst      = (float*)(ws + OFF_CST);
  float* hlast    = (float*)(ws + OFF_HLAST);

  // L3 stage LDS: 2 planes * 80*456 shorts = 145920 B + zbuf 16*81*4 = 5184
  const int FUSED_LDS = 151104;
  hipFuncSetAttribute(reinterpret_cast<const void*>(lstm_fused),
                      hipFuncAttributeMaxDynamicSharedMemorySize, FUSED_LDS);

  hipMemsetAsync(flags, 0, FLAGS_BYTES, stream);
  hipMemsetAsync(Hx0, 0, HX_TOT*4, stream);

  FusedArgs fa;
  fa.xs = xs;
  fa.Wx0 = Wx[0]; fa.Wx1 = Wx[1]; fa.Wx2 = Wx[2]; fa.Wx3 = Wx[3];
  fa.Wh0 = Wh[0]; fa.Wh1 = Wh[1]; fa.Wh2 = Wh[2]; fa.Wh3 = Wh[3];
  fa.b0 = bs[0];  fa.b1 = bs[1];  fa.b2 = bs[2];  fa.b3 = bs[3];
  fa.Hx0 = Hx0; fa.Hx1 = Hx1; fa.Hx2 = Hx2; fa.Hx3 = Hx3;
  fa.flags = flags; fa.cst = cst; fa.hlast = hlast;
  fa.t0 = 0; fa.TC = 1024; fa.Tlast = 1024;

  lstm_fused<<<240, 256, FUSED_LDS, stream>>>(fa);

  head_kernel<<<3, 256, 0, stream>>>(hlast, Wd, bd, out);
}